// Round 1
// baseline (191.636 us; speedup 1.0000x reference)
//
#include <hip/hip_runtime.h>

typedef _Float16 h2 __attribute__((ext_vector_type(2)));
typedef _Float16 h8 __attribute__((ext_vector_type(8)));
typedef float f32x4 __attribute__((ext_vector_type(4)));

#define B_  16
#define Q_  1024
#define C_  256
#define HW_ 1024
#define TQ  32
#define NT  512

__device__ __forceinline__ float fdot2f(h2 a, h2 b, float c) {
#if __has_builtin(__builtin_amdgcn_fdot2)
    return __builtin_amdgcn_fdot2(a, b, c, false);
#else
    return c + (float)a[0] * (float)b[0] + (float)a[1] * (float)b[1];
#endif
}

// ---------- prepass: keys f32 -> f16 ----------
__global__ void cvt_keys_f16(const float* __restrict__ src,
                             _Float16* __restrict__ dst, int n8) {
    int i = blockIdx.x * blockDim.x + threadIdx.x;
    if (i >= n8) return;
    const float4* s = (const float4*)src;
    float4 a = s[2 * i], b = s[2 * i + 1];
    h8 v;
    v[0] = (_Float16)a.x; v[1] = (_Float16)a.y; v[2] = (_Float16)a.z; v[3] = (_Float16)a.w;
    v[4] = (_Float16)b.x; v[5] = (_Float16)b.y; v[6] = (_Float16)b.z; v[7] = (_Float16)b.w;
    *(h8*)(dst + (size_t)i * 8) = v;
}

// ---------- fused: QK^T (f16 MFMA) + bias + softmax + conv1/relu/conv2 + add ----------
__global__ __launch_bounds__(NT, 2) void fused_attn_conv(
    const float* __restrict__ queries, const _Float16* __restrict__ keysh,
    const int* __restrict__ pos, const float* __restrict__ rel_bias,
    const float* __restrict__ w1, const float* __restrict__ b1,
    const float* __restrict__ w2, const float* __restrict__ b2,
    float* __restrict__ out)
{
    __shared__ _Float16 q_lds[TQ * C_];        // 16 KiB
    __shared__ _Float16 xmap[TQ * HW_];        // 64 KiB  (attn maps, f16)
    __shared__ float    bias_lds[63 * 64];     // 15.75 KiB (rel_bias, padded rows)
    __shared__ _Float16 Hbuf[2 * HW_ * 8];     // 32 KiB  (hidden, 2 images x 8ch f16)
    __shared__ float    red_max[4][TQ];
    __shared__ float    red_sum[4][TQ];
    __shared__ int2     pos_lds[TQ];

    const int tid  = threadIdx.x;
    const int bid  = blockIdx.x;
    const int swz  = (bid & 7) * 64 + (bid >> 3);   // XCD-chunked swizzle (512 % 8 == 0)
    const int batch = swz >> 5;
    const int tile  = swz & 31;

    // ---- stage: queries tile -> f16 LDS, rel_bias -> LDS, pos -> LDS ----
    {
        const float4* qsrc = (const float4*)(queries + (size_t)(batch * Q_ + tile * TQ) * C_);
        #pragma unroll
        for (int i = 0; i < 4; ++i) {
            int e4 = i * NT + tid;              // 2048 float4s
            float4 v = qsrc[e4];
            _Float16* d = &q_lds[e4 * 4];
            d[0] = (_Float16)v.x; d[1] = (_Float16)v.y;
            d[2] = (_Float16)v.z; d[3] = (_Float16)v.w;
        }
        for (int idx = tid; idx < 63 * 63; idx += NT) {
            int r = idx / 63;
            bias_lds[r * 64 + (idx - r * 63)] = rel_bias[idx];
        }
        if (tid < TQ)
            pos_lds[tid] = ((const int2*)pos)[batch * Q_ + tile * TQ + tid];
    }
    __syncthreads();

    // ---- GEMM: scores(32 x 1024) = Q(32x256) * K^T, fp16 MFMA 16x16x32 ----
    const int lane  = tid & 63;
    const int wv    = tid >> 6;        // 0..7
    const int mtile = wv & 1;          // which 16-row half of the 32-q tile
    const int nq    = wv >> 1;         // which 256-col quarter of the 1024 keys
    const int kgrp  = (lane >> 4) * 8; // k-offset within 32-k step
    const int arow  = mtile * 16 + (lane & 15);
    const int rowbase = mtile * 16 + ((lane >> 4) << 2);

    f32x4 acc[16];
    #pragma unroll
    for (int f = 0; f < 16; ++f) acc[f] = f32x4{0.f, 0.f, 0.f, 0.f};

    const _Float16* kb = keysh + (size_t)batch * (HW_ * C_)
                       + (size_t)(nq * 256 + (lane & 15)) * C_ + kgrp;
    #pragma unroll
    for (int ks = 0; ks < 8; ++ks) {
        h8 a = *(const h8*)&q_lds[arow * C_ + ks * 32 + kgrp];
        #pragma unroll
        for (int f = 0; f < 16; ++f) {
            h8 bfr = *(const h8*)(kb + f * (16 * C_) + ks * 32);
            acc[f] = __builtin_amdgcn_mfma_f32_16x16x32_f16(a, bfr, acc[f], 0, 0, 0);
        }
    }
    // C/D layout: col = lane&15 (+16*f), row = (lane>>4)*4 + r  (+mtile*16)

    // ---- softmax(scale*scores + bias) over 1024, rows = queries ----
    int p0r[4], p1r[4];
    #pragma unroll
    for (int r = 0; r < 4; ++r) {
        int2 pp = pos_lds[rowbase + r];
        p0r[r] = pp.x; p1r[r] = pp.y;
    }
    float mrow[4] = {-3e38f, -3e38f, -3e38f, -3e38f};
    #pragma unroll
    for (int f = 0; f < 16; ++f) {
        int col = nq * 256 + f * 16 + (lane & 15);
        int hh = col >> 5, ww = col & 31;
        #pragma unroll
        for (int r = 0; r < 4; ++r) {
            float s = acc[f][r] * 0.0625f
                    + bias_lds[(hh - p0r[r] + 31) * 64 + (ww - p1r[r] + 31)];
            acc[f][r] = s;
            mrow[r] = fmaxf(mrow[r], s);
        }
    }
    #pragma unroll
    for (int r = 0; r < 4; ++r) {
        mrow[r] = fmaxf(mrow[r], __shfl_xor(mrow[r], 1, 64));
        mrow[r] = fmaxf(mrow[r], __shfl_xor(mrow[r], 2, 64));
        mrow[r] = fmaxf(mrow[r], __shfl_xor(mrow[r], 4, 64));
        mrow[r] = fmaxf(mrow[r], __shfl_xor(mrow[r], 8, 64));
    }
    if ((lane & 15) == 0) {
        #pragma unroll
        for (int r = 0; r < 4; ++r) red_max[nq][rowbase + r] = mrow[r];
    }
    __syncthreads();

    float M4[4];
    #pragma unroll
    for (int r = 0; r < 4; ++r)
        M4[r] = fmaxf(fmaxf(red_max[0][rowbase + r], red_max[1][rowbase + r]),
                      fmaxf(red_max[2][rowbase + r], red_max[3][rowbase + r]));
    float sm[4] = {0.f, 0.f, 0.f, 0.f};
    #pragma unroll
    for (int f = 0; f < 16; ++f) {
        #pragma unroll
        for (int r = 0; r < 4; ++r) {
            float e = __expf(acc[f][r] - M4[r]);
            acc[f][r] = e;
            sm[r] += e;
        }
    }
    #pragma unroll
    for (int r = 0; r < 4; ++r) {
        sm[r] += __shfl_xor(sm[r], 1, 64);
        sm[r] += __shfl_xor(sm[r], 2, 64);
        sm[r] += __shfl_xor(sm[r], 4, 64);
        sm[r] += __shfl_xor(sm[r], 8, 64);
    }
    if ((lane & 15) == 0) {
        #pragma unroll
        for (int r = 0; r < 4; ++r) red_sum[nq][rowbase + r] = sm[r];
    }
    __syncthreads();

    float sinv[4];
    #pragma unroll
    for (int r = 0; r < 4; ++r) {
        float S = red_sum[0][rowbase + r] + red_sum[1][rowbase + r]
                + red_sum[2][rowbase + r] + red_sum[3][rowbase + r];
        sinv[r] = 1.0f / S;
    }
    #pragma unroll
    for (int f = 0; f < 16; ++f) {
        int col = nq * 256 + f * 16 + (lane & 15);
        #pragma unroll
        for (int r = 0; r < 4; ++r)
            xmap[(rowbase + r) * HW_ + col] = (_Float16)(acc[f][r] * sinv[r]);
    }
    __syncthreads();

    // ---- conv weights -> registers (packed f16 pairs for v_dot2_f32_f16) ----
    h2 w1p[8][5];   // taps paired (0,1)(2,3)(4,5)(6,7)(8,-)
    float b1r[8];
    #pragma unroll
    for (int ch = 0; ch < 8; ++ch) {
        b1r[ch] = b1[ch];
        #pragma unroll
        for (int j = 0; j < 5; ++j) {
            float wa = w1[ch * 9 + 2 * j];
            float wb = (2 * j + 1 < 9) ? w1[ch * 9 + 2 * j + 1] : 0.f;
            h2 t = {(_Float16)wa, (_Float16)wb};
            w1p[ch][j] = t;
        }
    }
    h2 w2p[9][4];   // channels paired (0,1)(2,3)(4,5)(6,7) per tap
    #pragma unroll
    for (int t9 = 0; t9 < 9; ++t9) {
        #pragma unroll
        for (int c2 = 0; c2 < 4; ++c2) {
            h2 t = {(_Float16)w2[(2 * c2) * 9 + t9], (_Float16)w2[(2 * c2 + 1) * 9 + t9]};
            w2p[t9][c2] = t;
        }
    }
    const float b2r = b2[0];

    float* outbase = out + (size_t)(batch * Q_ + tile * TQ) * HW_;

    // ---- conv: 16 steps x 2 images ----
    for (int step = 0; step < 16; ++step) {
        // conv1 + relu -> Hbuf (8ch f16 per pixel, 16B)
        #pragma unroll
        for (int i = 0; i < 4; ++i) {
            int px = i * NT + tid;          // 0..2047
            int g  = px >> 10;
            int p  = px & 1023;
            int y  = p >> 5, x = p & 31;
            int ql = step * 2 + g;
            const _Float16* xrow = &xmap[ql * HW_];
            _Float16 xn[9];
            #pragma unroll
            for (int dy = -1; dy <= 1; ++dy) {
                #pragma unroll
                for (int dx = -1; dx <= 1; ++dx) {
                    int yy = y + dy, xx = x + dx;
                    _Float16 v = (_Float16)0;
                    if ((unsigned)yy < 32u && (unsigned)xx < 32u)
                        v = xrow[yy * 32 + xx];
                    xn[(dy + 1) * 3 + (dx + 1)] = v;
                }
            }
            h2 xp0 = {xn[0], xn[1]}, xp1 = {xn[2], xn[3]}, xp2 = {xn[4], xn[5]},
               xp3 = {xn[6], xn[7]}, xp4 = {xn[8], (_Float16)0};
            h8 hv;
            #pragma unroll
            for (int ch = 0; ch < 8; ++ch) {
                float a1 = b1r[ch];
                a1 = fdot2f(xp0, w1p[ch][0], a1);
                a1 = fdot2f(xp1, w1p[ch][1], a1);
                a1 = fdot2f(xp2, w1p[ch][2], a1);
                a1 = fdot2f(xp3, w1p[ch][3], a1);
                a1 = fdot2f(xp4, w1p[ch][4], a1);
                hv[ch] = (_Float16)fmaxf(a1, 0.f);
            }
            *(h8*)&Hbuf[(size_t)px * 8] = hv;
        }
        __syncthreads();

        // conv2 + residual add -> out
        #pragma unroll
        for (int i = 0; i < 4; ++i) {
            int px = i * NT + tid;
            int g  = px >> 10;
            int p  = px & 1023;
            int y  = p >> 5, x = p & 31;
            int ql = step * 2 + g;
            float a2 = b2r;
            #pragma unroll
            for (int dy = -1; dy <= 1; ++dy) {
                int yy = y + dy;
                if ((unsigned)yy < 32u) {
                    #pragma unroll
                    for (int dx = -1; dx <= 1; ++dx) {
                        int xx = x + dx;
                        if ((unsigned)xx < 32u) {
                            const uint4 u = *(const uint4*)&Hbuf[((g << 10) + yy * 32 + xx) * 8];
                            const int t = (dy + 1) * 3 + (dx + 1);
                            a2 = fdot2f(__builtin_bit_cast(h2, u.x), w2p[t][0], a2);
                            a2 = fdot2f(__builtin_bit_cast(h2, u.y), w2p[t][1], a2);
                            a2 = fdot2f(__builtin_bit_cast(h2, u.z), w2p[t][2], a2);
                            a2 = fdot2f(__builtin_bit_cast(h2, u.w), w2p[t][3], a2);
                        }
                    }
                }
            }
            float xv = (float)xmap[ql * HW_ + p];
            outbase[(size_t)ql * HW_ + p] = xv + a2;
        }
        __syncthreads();
    }
}

extern "C" void kernel_launch(void* const* d_in, const int* in_sizes, int n_in,
                              void* d_out, int out_size, void* d_ws, size_t ws_size,
                              hipStream_t stream) {
    const float* queries  = (const float*)d_in[0];
    const float* keys     = (const float*)d_in[1];
    const int*   pos      = (const int*)d_in[2];
    const float* rel_bias = (const float*)d_in[3];
    const float* w1       = (const float*)d_in[4];
    const float* b1       = (const float*)d_in[5];
    const float* w2       = (const float*)d_in[6];
    const float* b2       = (const float*)d_in[7];
    float* out = (float*)d_out;

    _Float16* keysh = (_Float16*)d_ws;   // 8 MiB

    const int n8 = (B_ * HW_ * C_) / 8;  // 524288
    cvt_keys_f16<<<dim3(n8 / 256), dim3(256), 0, stream>>>(keys, keysh, n8);
    fused_attn_conv<<<dim3(B_ * (Q_ / TQ)), dim3(NT), 0, stream>>>(
        queries, keysh, pos, rel_bias, w1, b1, w2, b2, out);
}

// Round 2
// 145.242 us; speedup vs baseline: 1.3194x; 1.3194x over previous
//
#include <hip/hip_runtime.h>

typedef _Float16 h2 __attribute__((ext_vector_type(2)));
typedef _Float16 h8 __attribute__((ext_vector_type(8)));
typedef float f32x4 __attribute__((ext_vector_type(4)));

#define B_  16
#define Q_  1024
#define C_  256
#define HW_ 1024
#define TQ  16
#define NT  512
#define QLD 264   // q_lds leading dim in halfwords: 256 + 8 pad (breaks 512B-stride bank conflict)

__device__ __forceinline__ float fdot2f(h2 a, h2 b, float c) {
#if __has_builtin(__builtin_amdgcn_fdot2)
    return __builtin_amdgcn_fdot2(a, b, c, false);
#else
    return c + (float)a[0] * (float)b[0] + (float)a[1] * (float)b[1];
#endif
}
__device__ __forceinline__ h2 u2h(unsigned u) { return __builtin_bit_cast(h2, u); }

// ---------- prepass: keys f32 -> f16 ----------
__global__ void cvt_keys_f16(const float* __restrict__ src,
                             _Float16* __restrict__ dst, int n8) {
    int i = blockIdx.x * blockDim.x + threadIdx.x;
    if (i >= n8) return;
    const float4* s = (const float4*)src;
    float4 a = s[2 * i], b = s[2 * i + 1];
    h8 v;
    v[0] = (_Float16)a.x; v[1] = (_Float16)a.y; v[2] = (_Float16)a.z; v[3] = (_Float16)a.w;
    v[4] = (_Float16)b.x; v[5] = (_Float16)b.y; v[6] = (_Float16)b.z; v[7] = (_Float16)b.w;
    *(h8*)(dst + (size_t)i * 8) = v;
}

// ---------- fused: QK^T (f16 MFMA) + bias + softmax + conv1/relu/conv2 + add ----------
__global__ __launch_bounds__(NT, 4) void fused_attn_conv(
    const float* __restrict__ queries, const _Float16* __restrict__ keysh,
    const int* __restrict__ pos, const float* __restrict__ rel_bias,
    const float* __restrict__ w1, const float* __restrict__ b1,
    const float* __restrict__ w2, const float* __restrict__ b2,
    float* __restrict__ out)
{
    __shared__ _Float16 q_lds[TQ * QLD];       // 8.25 KiB
    __shared__ _Float16 xmap[TQ * HW_];        // 32 KiB
    __shared__ float    bias_lds[63 * 64];     // 15.75 KiB
    __shared__ _Float16 Hbuf[HW_ * 8];         // 16 KiB (one image, 8ch f16)
    __shared__ float    red_max[8][TQ];
    __shared__ float    red_sum[8][TQ];
    __shared__ int2     pos_lds[TQ];
    __shared__ float    wstage[153];           // w1(72) b1(8) w2(72) b2(1)

    const int tid = threadIdx.x;
    const int bid = blockIdx.x;
    const int swz = (bid & 7) * 128 + (bid >> 3);   // XCD-chunked swizzle (1024 % 8 == 0)
    const int batch = swz >> 6;
    const int tile  = swz & 63;

    // ---- stage: queries tile -> f16 LDS (padded rows), rel_bias, pos, conv weights ----
    {
        const float4* qsrc = (const float4*)(queries + (size_t)(batch * Q_ + tile * TQ) * C_);
        #pragma unroll
        for (int i = 0; i < 2; ++i) {
            int e4 = i * NT + tid;              // 0..1023 float4s
            float4 v = qsrc[e4];
            int row = e4 >> 6, col4 = e4 & 63;
            _Float16* d = &q_lds[row * QLD + col4 * 4];
            d[0] = (_Float16)v.x; d[1] = (_Float16)v.y;
            d[2] = (_Float16)v.z; d[3] = (_Float16)v.w;
        }
        for (int idx = tid; idx < 63 * 63; idx += NT) {
            int r = idx / 63;
            bias_lds[r * 64 + (idx - r * 63)] = rel_bias[idx];
        }
        if (tid < TQ)
            pos_lds[tid] = ((const int2*)pos)[batch * Q_ + tile * TQ + tid];
        if (tid < 72)        wstage[tid] = w1[tid];
        else if (tid < 80)   wstage[tid] = b1[tid - 72];
        else if (tid < 152)  wstage[tid] = w2[tid - 80];
        else if (tid == 152) wstage[tid] = b2[0];
    }
    __syncthreads();

    // ---- GEMM: scores(16 x 1024) = Q(16x256) * K^T, fp16 MFMA 16x16x32 ----
    const int lane = tid & 63;
    const int wv   = tid >> 6;         // 0..7 -> 128-col slice each
    const int kgrp = (lane >> 4) * 8;
    const int arow = lane & 15;
    const int rowbase = (lane >> 4) << 2;

    f32x4 acc[8];
    #pragma unroll
    for (int f = 0; f < 8; ++f) acc[f] = f32x4{0.f, 0.f, 0.f, 0.f};

    const _Float16* kb = keysh + (size_t)batch * (HW_ * C_)
                       + (size_t)(wv * 128 + (lane & 15)) * C_ + kgrp;
    #pragma unroll
    for (int ks = 0; ks < 8; ++ks) {
        h8 a = *(const h8*)&q_lds[arow * QLD + ks * 32 + kgrp];
        #pragma unroll
        for (int f = 0; f < 8; ++f) {
            h8 bfr = *(const h8*)(kb + f * (16 * C_) + ks * 32);
            acc[f] = __builtin_amdgcn_mfma_f32_16x16x32_f16(a, bfr, acc[f], 0, 0, 0);
        }
    }
    // C/D layout: col = wv*128 + f*16 + (lane&15), row = rowbase + r

    // ---- softmax(scale*scores + bias) over 1024 ----
    int p0r[4], p1r[4];
    #pragma unroll
    for (int r = 0; r < 4; ++r) {
        int2 pp = pos_lds[rowbase + r];
        p0r[r] = pp.x; p1r[r] = pp.y;
    }
    float mrow[4] = {-3e38f, -3e38f, -3e38f, -3e38f};
    #pragma unroll
    for (int f = 0; f < 8; ++f) {
        int col = wv * 128 + f * 16 + (lane & 15);
        int hh = col >> 5, ww = col & 31;
        #pragma unroll
        for (int r = 0; r < 4; ++r) {
            float s = acc[f][r] * 0.0625f
                    + bias_lds[(hh - p0r[r] + 31) * 64 + (ww - p1r[r] + 31)];
            acc[f][r] = s;
            mrow[r] = fmaxf(mrow[r], s);
        }
    }
    #pragma unroll
    for (int r = 0; r < 4; ++r) {
        mrow[r] = fmaxf(mrow[r], __shfl_xor(mrow[r], 1, 64));
        mrow[r] = fmaxf(mrow[r], __shfl_xor(mrow[r], 2, 64));
        mrow[r] = fmaxf(mrow[r], __shfl_xor(mrow[r], 4, 64));
        mrow[r] = fmaxf(mrow[r], __shfl_xor(mrow[r], 8, 64));
    }
    if ((lane & 15) == 0) {
        #pragma unroll
        for (int r = 0; r < 4; ++r) red_max[wv][rowbase + r] = mrow[r];
    }
    __syncthreads();

    float M4[4];
    #pragma unroll
    for (int r = 0; r < 4; ++r) {
        float m = red_max[0][rowbase + r];
        #pragma unroll
        for (int w = 1; w < 8; ++w) m = fmaxf(m, red_max[w][rowbase + r]);
        M4[r] = m;
    }
    float sm[4] = {0.f, 0.f, 0.f, 0.f};
    #pragma unroll
    for (int f = 0; f < 8; ++f) {
        #pragma unroll
        for (int r = 0; r < 4; ++r) {
            float e = __expf(acc[f][r] - M4[r]);
            acc[f][r] = e;
            sm[r] += e;
        }
    }
    #pragma unroll
    for (int r = 0; r < 4; ++r) {
        sm[r] += __shfl_xor(sm[r], 1, 64);
        sm[r] += __shfl_xor(sm[r], 2, 64);
        sm[r] += __shfl_xor(sm[r], 4, 64);
        sm[r] += __shfl_xor(sm[r], 8, 64);
    }
    if ((lane & 15) == 0) {
        #pragma unroll
        for (int r = 0; r < 4; ++r) red_sum[wv][rowbase + r] = sm[r];
    }
    __syncthreads();

    float sinv[4];
    #pragma unroll
    for (int r = 0; r < 4; ++r) {
        float S = red_sum[0][rowbase + r];
        #pragma unroll
        for (int w = 1; w < 8; ++w) S += red_sum[w][rowbase + r];
        sinv[r] = 1.0f / S;
    }
    #pragma unroll
    for (int f = 0; f < 8; ++f) {
        int col = wv * 128 + f * 16 + (lane & 15);
        #pragma unroll
        for (int r = 0; r < 4; ++r)
            xmap[(rowbase + r) * HW_ + col] = (_Float16)(acc[f][r] * sinv[r]);
    }
    __syncthreads();

    // ---- conv weights: pack f16 pairs, hoist to SGPRs (wave-uniform) ----
    unsigned w1s[8][5];
    float b1r[8];
    #pragma unroll
    for (int ch = 0; ch < 8; ++ch) {
        b1r[ch] = wstage[72 + ch];
        #pragma unroll
        for (int j = 0; j < 5; ++j) {
            float wa = wstage[ch * 9 + 2 * j];
            float wb = (2 * j + 1 < 9) ? wstage[ch * 9 + 2 * j + 1] : 0.f;
            h2 t = {(_Float16)wa, (_Float16)wb};
            w1s[ch][j] = __builtin_amdgcn_readfirstlane(__builtin_bit_cast(unsigned, t));
        }
    }
    unsigned w2s[9][4];
    #pragma unroll
    for (int t9 = 0; t9 < 9; ++t9) {
        #pragma unroll
        for (int c2 = 0; c2 < 4; ++c2) {
            h2 t = {(_Float16)wstage[80 + (2 * c2) * 9 + t9],
                    (_Float16)wstage[80 + (2 * c2 + 1) * 9 + t9]};
            w2s[t9][c2] = __builtin_amdgcn_readfirstlane(__builtin_bit_cast(unsigned, t));
        }
    }
    const float b2r = wstage[152];

    float* outbase = out + (size_t)(batch * Q_ + tile * TQ) * HW_;

    // ---- conv: 16 steps x 1 image (1024 px), 2 px/thread/phase ----
    for (int step = 0; step < 16; ++step) {
        const _Float16* xrow = &xmap[step * HW_];
        #pragma unroll
        for (int i = 0; i < 2; ++i) {
            int px = i * NT + tid;          // 0..1023
            int y = px >> 5, x = px & 31;
            _Float16 xn[9];
            #pragma unroll
            for (int dy = -1; dy <= 1; ++dy) {
                #pragma unroll
                for (int dx = -1; dx <= 1; ++dx) {
                    int yy = y + dy, xx = x + dx;
                    _Float16 v = (_Float16)0;
                    if ((unsigned)yy < 32u && (unsigned)xx < 32u)
                        v = xrow[yy * 32 + xx];
                    xn[(dy + 1) * 3 + (dx + 1)] = v;
                }
            }
            h2 xp0 = {xn[0], xn[1]}, xp1 = {xn[2], xn[3]}, xp2 = {xn[4], xn[5]},
               xp3 = {xn[6], xn[7]}, xp4 = {xn[8], (_Float16)0};
            h8 hv;
            #pragma unroll
            for (int ch = 0; ch < 8; ++ch) {
                float a1 = b1r[ch];
                a1 = fdot2f(xp0, u2h(w1s[ch][0]), a1);
                a1 = fdot2f(xp1, u2h(w1s[ch][1]), a1);
                a1 = fdot2f(xp2, u2h(w1s[ch][2]), a1);
                a1 = fdot2f(xp3, u2h(w1s[ch][3]), a1);
                a1 = fdot2f(xp4, u2h(w1s[ch][4]), a1);
                hv[ch] = (_Float16)fmaxf(a1, 0.f);
            }
            *(h8*)&Hbuf[(size_t)px * 8] = hv;
        }
        __syncthreads();

        #pragma unroll
        for (int i = 0; i < 2; ++i) {
            int px = i * NT + tid;
            int y = px >> 5, x = px & 31;
            float a2 = b2r;
            #pragma unroll
            for (int dy = -1; dy <= 1; ++dy) {
                int yy = y + dy;
                if ((unsigned)yy < 32u) {
                    #pragma unroll
                    for (int dx = -1; dx <= 1; ++dx) {
                        int xx = x + dx;
                        if ((unsigned)xx < 32u) {
                            const uint4 u = *(const uint4*)&Hbuf[(yy * 32 + xx) * 8];
                            const int t = (dy + 1) * 3 + (dx + 1);
                            a2 = fdot2f(__builtin_bit_cast(h2, u.x), u2h(w2s[t][0]), a2);
                            a2 = fdot2f(__builtin_bit_cast(h2, u.y), u2h(w2s[t][1]), a2);
                            a2 = fdot2f(__builtin_bit_cast(h2, u.z), u2h(w2s[t][2]), a2);
                            a2 = fdot2f(__builtin_bit_cast(h2, u.w), u2h(w2s[t][3]), a2);
                        }
                    }
                }
            }
            float xv = (float)xrow[px];
            outbase[(size_t)step * HW_ + px] = xv + a2;
        }
        __syncthreads();
    }
}

extern "C" void kernel_launch(void* const* d_in, const int* in_sizes, int n_in,
                              void* d_out, int out_size, void* d_ws, size_t ws_size,
                              hipStream_t stream) {
    const float* queries  = (const float*)d_in[0];
    const float* keys     = (const float*)d_in[1];
    const int*   pos      = (const int*)d_in[2];
    const float* rel_bias = (const float*)d_in[3];
    const float* w1       = (const float*)d_in[4];
    const float* b1       = (const float*)d_in[5];
    const float* w2       = (const float*)d_in[6];
    const float* b2       = (const float*)d_in[7];
    float* out = (float*)d_out;

    _Float16* keysh = (_Float16*)d_ws;   // 8 MiB

    const int n8 = (B_ * HW_ * C_) / 8;  // 524288
    cvt_keys_f16<<<dim3(n8 / 256), dim3(256), 0, stream>>>(keys, keysh, n8);
    fused_attn_conv<<<dim3(B_ * (Q_ / TQ)), dim3(NT), 0, stream>>>(
        queries, keysh, pos, rel_bias, w1, b1, w2, b2, out);
}

// Round 3
// 133.681 us; speedup vs baseline: 1.4335x; 1.0865x over previous
//
#include <hip/hip_runtime.h>

typedef _Float16 h2 __attribute__((ext_vector_type(2)));
typedef _Float16 h8 __attribute__((ext_vector_type(8)));
typedef float f32x4 __attribute__((ext_vector_type(4)));

#define B_  16
#define Q_  1024
#define C_  256
#define HW_ 1024
#define TQ  16
#define NT  512
#define QLD 264   // q_lds leading dim (halfwords): 256 + 8 pad

__device__ __forceinline__ float fdot2f(h2 a, h2 b, float c) {
#if __has_builtin(__builtin_amdgcn_fdot2)
    return __builtin_amdgcn_fdot2(a, b, c, false);
#else
    return c + (float)a[0] * (float)b[0] + (float)a[1] * (float)b[1];
#endif
}
__device__ __forceinline__ h2 u2h(unsigned u) { return __builtin_bit_cast(h2, u); }
__device__ __forceinline__ unsigned h2u(h2 h) { return __builtin_bit_cast(unsigned, h); }
__device__ __forceinline__ float rflf(float v) {
    return __builtin_bit_cast(float, __builtin_amdgcn_readfirstlane(__builtin_bit_cast(int, v)));
}

// ---------- prepass: keys f32 -> f16 ----------
__global__ void cvt_keys_f16(const float* __restrict__ src,
                             _Float16* __restrict__ dst, int n8) {
    int i = blockIdx.x * blockDim.x + threadIdx.x;
    if (i >= n8) return;
    const float4* s = (const float4*)src;
    float4 a = s[2 * i], b = s[2 * i + 1];
    h8 v;
    v[0] = (_Float16)a.x; v[1] = (_Float16)a.y; v[2] = (_Float16)a.z; v[3] = (_Float16)a.w;
    v[4] = (_Float16)b.x; v[5] = (_Float16)b.y; v[6] = (_Float16)b.z; v[7] = (_Float16)b.w;
    *(h8*)(dst + (size_t)i * 8) = v;
}

// ---------- fused: QK^T (f16 MFMA) + bias + softmax + conv1/relu/conv2 + add ----------
__global__ __launch_bounds__(NT, 4) void fused_attn_conv(
    const float* __restrict__ queries, const _Float16* __restrict__ keysh,
    const int* __restrict__ pos, const float* __restrict__ rel_bias,
    const float* __restrict__ w1, const float* __restrict__ b1,
    const float* __restrict__ w2, const float* __restrict__ b2,
    float* __restrict__ out)
{
    __shared__ _Float16 xmap[TQ * HW_];              // 32 KiB (attn maps; persists)
    __shared__ __align__(16) char ubuf[32768];       // 32 KiB overlay:
    // phase A: q_lds (16*264*2 = 8448 B) + bias_lds (63*64*2 = 8064 B)
    // phase B: Hbuf (2 images * 1024 px * 16 B)
    __shared__ float red_max[8][TQ];
    __shared__ float red_sum[8][TQ];
    __shared__ int2  pos_lds[TQ];
    __shared__ float wstage[153];                    // w1(72) b1(8) w2(72) b2(1)

    _Float16* q_lds    = (_Float16*)ubuf;
    _Float16* bias_lds = (_Float16*)(ubuf + 8448);
    char*     Hb       = ubuf;

    const int tid = threadIdx.x;
    const int bid = blockIdx.x;
    const int swz = (bid & 7) * 128 + (bid >> 3);    // XCD-chunked swizzle (1024 % 8 == 0)
    const int batch = swz >> 6;
    const int tile  = swz & 63;

    // ---- stage: queries -> f16 LDS, rel_bias -> f16 LDS, pos, conv weights ----
    {
        const float4* qsrc = (const float4*)(queries + (size_t)(batch * Q_ + tile * TQ) * C_);
        #pragma unroll
        for (int i = 0; i < 2; ++i) {
            int e4 = i * NT + tid;                   // 0..1023
            float4 v = qsrc[e4];
            int row = e4 >> 6, col4 = e4 & 63;
            _Float16* d = &q_lds[row * QLD + col4 * 4];
            d[0] = (_Float16)v.x; d[1] = (_Float16)v.y;
            d[2] = (_Float16)v.z; d[3] = (_Float16)v.w;
        }
        for (int idx = tid; idx < 63 * 63; idx += NT) {
            int r = idx / 63;
            bias_lds[r * 64 + (idx - r * 63)] = (_Float16)rel_bias[idx];
        }
        if (tid < TQ)
            pos_lds[tid] = ((const int2*)pos)[batch * Q_ + tile * TQ + tid];
        if (tid < 72)        wstage[tid] = w1[tid];
        else if (tid < 80)   wstage[tid] = b1[tid - 72];
        else if (tid < 152)  wstage[tid] = w2[tid - 80];
        else if (tid == 152) wstage[tid] = b2[0];
    }
    __syncthreads();

    // ---- GEMM: scores(16 x 1024) = Q(16x256) * K^T, fp16 MFMA 16x16x32 ----
    const int lane = tid & 63;
    const int wv   = tid >> 6;          // 0..7 -> 128-col slice
    const int kgrp = (lane >> 4) * 8;
    const int arow = lane & 15;
    const int rowbase = (lane >> 4) << 2;

    f32x4 acc[8];
    #pragma unroll
    for (int f = 0; f < 8; ++f) acc[f] = f32x4{0.f, 0.f, 0.f, 0.f};

    const _Float16* kb = keysh + (size_t)batch * (HW_ * C_)
                       + (size_t)(wv * 128 + (lane & 15)) * C_ + kgrp;
    #pragma unroll
    for (int ks = 0; ks < 8; ++ks) {
        h8 a = *(const h8*)&q_lds[arow * QLD + ks * 32 + kgrp];
        #pragma unroll
        for (int f = 0; f < 8; ++f) {
            h8 bfr = *(const h8*)(kb + f * (16 * C_) + ks * 32);
            acc[f] = __builtin_amdgcn_mfma_f32_16x16x32_f16(a, bfr, acc[f], 0, 0, 0);
        }
    }

    // ---- softmax(scale*scores + bias) over 1024 ----
    int p0r[4], p1r[4];
    #pragma unroll
    for (int r = 0; r < 4; ++r) {
        int2 pp = pos_lds[rowbase + r];
        p0r[r] = pp.x; p1r[r] = pp.y;
    }
    float mrow[4] = {-3e38f, -3e38f, -3e38f, -3e38f};
    #pragma unroll
    for (int f = 0; f < 8; ++f) {
        int col = wv * 128 + f * 16 + (lane & 15);
        int hh = col >> 5, ww = col & 31;
        #pragma unroll
        for (int r = 0; r < 4; ++r) {
            float s = acc[f][r] * 0.0625f
                    + (float)bias_lds[(hh - p0r[r] + 31) * 64 + (ww - p1r[r] + 31)];
            acc[f][r] = s;
            mrow[r] = fmaxf(mrow[r], s);
        }
    }
    #pragma unroll
    for (int r = 0; r < 4; ++r) {
        mrow[r] = fmaxf(mrow[r], __shfl_xor(mrow[r], 1, 64));
        mrow[r] = fmaxf(mrow[r], __shfl_xor(mrow[r], 2, 64));
        mrow[r] = fmaxf(mrow[r], __shfl_xor(mrow[r], 4, 64));
        mrow[r] = fmaxf(mrow[r], __shfl_xor(mrow[r], 8, 64));
    }
    if ((lane & 15) == 0) {
        #pragma unroll
        for (int r = 0; r < 4; ++r) red_max[wv][rowbase + r] = mrow[r];
    }
    __syncthreads();

    float M4[4];
    #pragma unroll
    for (int r = 0; r < 4; ++r) {
        float m = red_max[0][rowbase + r];
        #pragma unroll
        for (int w = 1; w < 8; ++w) m = fmaxf(m, red_max[w][rowbase + r]);
        M4[r] = m;
    }
    float sm[4] = {0.f, 0.f, 0.f, 0.f};
    #pragma unroll
    for (int f = 0; f < 8; ++f) {
        #pragma unroll
        for (int r = 0; r < 4; ++r) {
            float e = __expf(acc[f][r] - M4[r]);
            acc[f][r] = e;
            sm[r] += e;
        }
    }
    #pragma unroll
    for (int r = 0; r < 4; ++r) {
        sm[r] += __shfl_xor(sm[r], 1, 64);
        sm[r] += __shfl_xor(sm[r], 2, 64);
        sm[r] += __shfl_xor(sm[r], 4, 64);
        sm[r] += __shfl_xor(sm[r], 8, 64);
    }
    if ((lane & 15) == 0) {
        #pragma unroll
        for (int r = 0; r < 4; ++r) red_sum[wv][rowbase + r] = sm[r];
    }
    __syncthreads();

    float sinv[4];
    #pragma unroll
    for (int r = 0; r < 4; ++r) {
        float S = red_sum[0][rowbase + r];
        #pragma unroll
        for (int w = 1; w < 8; ++w) S += red_sum[w][rowbase + r];
        sinv[r] = 1.0f / S;
    }
    #pragma unroll
    for (int f = 0; f < 8; ++f) {
        int col = wv * 128 + f * 16 + (lane & 15);
        #pragma unroll
        for (int r = 0; r < 4; ++r)
            xmap[(rowbase + r) * HW_ + col] = (_Float16)(acc[f][r] * sinv[r]);
    }
    __syncthreads();   // after this, q_lds/bias_lds are dead; ubuf becomes Hbuf

    // ---- conv weights -> SGPR-resident packed f16 pairs ----
    unsigned wA[8][3], wB[8][3];
    float b1r[8];
    #pragma unroll
    for (int ch = 0; ch < 8; ++ch) {
        b1r[ch] = rflf(wstage[72 + ch]);
        #pragma unroll
        for (int r = 0; r < 3; ++r) {
            h2 a = {(_Float16)wstage[ch * 9 + r * 3 + 0], (_Float16)wstage[ch * 9 + r * 3 + 1]};
            h2 b = {(_Float16)wstage[ch * 9 + r * 3 + 2], (_Float16)0.f};
            wA[ch][r] = __builtin_amdgcn_readfirstlane(h2u(a));
            wB[ch][r] = __builtin_amdgcn_readfirstlane(h2u(b));
        }
    }
    unsigned w2s[9][4];
    #pragma unroll
    for (int t9 = 0; t9 < 9; ++t9) {
        #pragma unroll
        for (int c2 = 0; c2 < 4; ++c2) {
            h2 t = {(_Float16)wstage[80 + (2 * c2) * 9 + t9],
                    (_Float16)wstage[80 + (2 * c2 + 1) * 9 + t9]};
            w2s[t9][c2] = __builtin_amdgcn_readfirstlane(h2u(t));
        }
    }
    const float b2r = rflf(wstage[152]);

    // ---- conv mapping: thread -> (img, y, 4-px x-run) ----
    const int t8  = tid & 255;
    const int img = tid >> 8;            // 0/1
    const int x0  = (t8 & 7) << 2;       // 0,4,...,28
    const int y   = t8 >> 3;             // 0..31
    const unsigned mW = (unsigned)((y & 7) << 4);      // Hbuf write swizzle
    char* const HbImg = Hb + img * 16384;
    float* const outp = out + (size_t)(batch * Q_ + tile * TQ) * HW_;

    for (int step = 0; step < 8; ++step) {
        const int ql = step * 2 + img;
        const _Float16* xim = &xmap[ql * HW_];

        // --- conv1 + relu -> Hbuf (4 px) ---
        unsigned Pm[3], A0[3], Pc[3], A1[3], Pe[3], E4[3];
        #pragma unroll
        for (int dy = 0; dy < 3; ++dy) {
            int yy = y + dy - 1;
            unsigned b0v = 0, b1v = 0, em = 0, e4 = 0;
            if ((unsigned)yy < 32u) {
                const _Float16* row = xim + yy * 32 + x0;
                uint2 bb = *(const uint2*)row;                   // v0..v3
                b0v = bb.x; b1v = bb.y;
                if (x0 > 0)      em = *(const unsigned short*)(row - 1);
                if (x0 + 4 < 32) e4 = *(const unsigned short*)(row + 4);
            }
            Pm[dy] = (em & 0xffffu) | (b0v << 16);   // (v-1, v0)
            A0[dy] = b0v;                            // (v0, v1)
            Pc[dy] = (b0v >> 16) | (b1v << 16);      // (v1, v2)
            A1[dy] = b1v;                            // (v2, v3)
            Pe[dy] = (b1v >> 16) | (e4 << 16);       // (v3, v4)
            E4[dy] = e4;                             // (v4, 0)
        }
        h8 hv0, hv1, hv2, hv3;
        #pragma unroll
        for (int ch = 0; ch < 8; ++ch) {
            float s0 = b1r[ch], s1 = b1r[ch], s2 = b1r[ch], s3 = b1r[ch];
            #pragma unroll
            for (int dy = 0; dy < 3; ++dy) {
                h2 wa = u2h(wA[ch][dy]), wb = u2h(wB[ch][dy]);
                s0 = fdot2f(u2h(Pm[dy]), wa, s0); s0 = fdot2f(u2h(Pc[dy]), wb, s0);
                s1 = fdot2f(u2h(A0[dy]), wa, s1); s1 = fdot2f(u2h(A1[dy]), wb, s1);
                s2 = fdot2f(u2h(Pc[dy]), wa, s2); s2 = fdot2f(u2h(Pe[dy]), wb, s2);
                s3 = fdot2f(u2h(A1[dy]), wa, s3); s3 = fdot2f(u2h(E4[dy]), wb, s3);
            }
            hv0[ch] = (_Float16)fmaxf(s0, 0.f);
            hv1[ch] = (_Float16)fmaxf(s1, 0.f);
            hv2[ch] = (_Float16)fmaxf(s2, 0.f);
            hv3[ch] = (_Float16)fmaxf(s3, 0.f);
        }
        {
            char* wbp = HbImg + (y << 9);
            *(h8*)(wbp + (((x0 + 0) << 4) ^ mW)) = hv0;
            *(h8*)(wbp + (((x0 + 1) << 4) ^ mW)) = hv1;
            *(h8*)(wbp + (((x0 + 2) << 4) ^ mW)) = hv2;
            *(h8*)(wbp + (((x0 + 3) << 4) ^ mW)) = hv3;
        }
        __syncthreads();

        // --- conv2 + residual -> out (4 px) ---
        float a2[4] = {b2r, b2r, b2r, b2r};
        #pragma unroll
        for (int dy = 0; dy < 3; ++dy) {
            int yy = y + dy - 1;
            uint4 Hv[6];
            if ((unsigned)yy < 32u) {
                char* rb = HbImg + (yy << 9);
                unsigned m = (unsigned)((yy & 7) << 4);
                #pragma unroll
                for (int k = 0; k < 6; ++k) {
                    int c = x0 - 1 + k;
                    if ((unsigned)c < 32u)
                        Hv[k] = *(const uint4*)(rb + (((unsigned)(c << 4)) ^ m));
                    else
                        Hv[k] = uint4{0u, 0u, 0u, 0u};
                }
            } else {
                #pragma unroll
                for (int k = 0; k < 6; ++k) Hv[k] = uint4{0u, 0u, 0u, 0u};
            }
            #pragma unroll
            for (int j = 0; j < 4; ++j) {
                #pragma unroll
                for (int dx = 0; dx < 3; ++dx) {
                    const int tt = dy * 3 + dx;
                    const uint4 uu = Hv[j + dx];
                    a2[j] = fdot2f(u2h(uu.x), u2h(w2s[tt][0]), a2[j]);
                    a2[j] = fdot2f(u2h(uu.y), u2h(w2s[tt][1]), a2[j]);
                    a2[j] = fdot2f(u2h(uu.z), u2h(w2s[tt][2]), a2[j]);
                    a2[j] = fdot2f(u2h(uu.w), u2h(w2s[tt][3]), a2[j]);
                }
            }
        }
        {
            const _Float16* xr4 = xim + y * 32 + x0;
            uint2 rr = *(const uint2*)xr4;
            h2 lo = u2h(rr.x), hi = u2h(rr.y);
            float4 o;
            o.x = (float)lo[0] + a2[0];
            o.y = (float)lo[1] + a2[1];
            o.z = (float)hi[0] + a2[2];
            o.w = (float)hi[1] + a2[3];
            *(float4*)(outp + (size_t)ql * HW_ + y * 32 + x0) = o;
        }
        __syncthreads();
    }
}

extern "C" void kernel_launch(void* const* d_in, const int* in_sizes, int n_in,
                              void* d_out, int out_size, void* d_ws, size_t ws_size,
                              hipStream_t stream) {
    const float* queries  = (const float*)d_in[0];
    const float* keys     = (const float*)d_in[1];
    const int*   pos      = (const int*)d_in[2];
    const float* rel_bias = (const float*)d_in[3];
    const float* w1       = (const float*)d_in[4];
    const float* b1       = (const float*)d_in[5];
    const float* w2       = (const float*)d_in[6];
    const float* b2       = (const float*)d_in[7];
    float* out = (float*)d_out;

    _Float16* keysh = (_Float16*)d_ws;   // 8 MiB

    const int n8 = (B_ * HW_ * C_) / 8;  // 524288
    cvt_keys_f16<<<dim3(n8 / 256), dim3(256), 0, stream>>>(keys, keysh, n8);
    fused_attn_conv<<<dim3(B_ * (Q_ / TQ)), dim3(NT), 0, stream>>>(
        queries, keysh, pos, rel_bias, w1, b1, w2, b2, out);
}